// Round 6
// baseline (218.120 us; speedup 1.0000x reference)
//
#include <hip/hip_runtime.h>
#include <stdint.h>

// DotProductAttention, B=8 S=4096 D=64 fp32, key-masked at valid_len[b].
// Error-compensated bf16 MFMA flash attention, v3.1:
//  - prepack: K,V -> bf16 hi/lo tiles in ws (16KB per 32-key chunk).
//  - attn: block = 4 waves (2 row-groups x 2 key-stripe pair), 64-row Q tile.
//    K staged to LDS via global_load_lds (K-only: 32KB dbuf -> 4-5 blocks/CU);
//    V fragments read directly from packed ws (L2) into regs AFTER the QK
//    accumulators die (peak VGPR ~120 < 128 cap, no spill).
//    Swapped QK^T (mfma(K,Q)); P built in-register via v_cvt_pk_bf16_f32 +
//    v_permlane32_swap_b32; defer-max online softmax.
//  - split-K: grid (b, qt, slice of 1024 keys) = 2048 blocks -> HW dispatcher
//    balances; per-slice partials (m, l, unnormalized o) in ws; combine kernel
//    merges. Single-active-slice tiles write Out directly.

constexpr int BB = 8;
constexpr int SS = 4096;
constexpr int DH = 64;
constexpr int CH = 32;              // keys per chunk
constexpr int NKT = SS / CH;        // 128 chunks per batch
constexpr int TILE_SHORTS = 8192;   // 16 KB: Khi 4K | Klo 4K | Vhi 4K | Vlo 4K
constexpr int KO_SHORTS = 4096;     // K-only part staged to LDS (8 KB)

typedef short  bfrag  __attribute__((ext_vector_type(8)));   // 8 bf16
typedef float  f32x16 __attribute__((ext_vector_type(16)));
typedef unsigned int uvec4 __attribute__((ext_vector_type(4)));

__device__ __forceinline__ unsigned short f2bf(float x) {
  unsigned u = __builtin_bit_cast(unsigned, x);
  u += 0x7fffu + ((u >> 16) & 1u);   // RNE
  return (unsigned short)(u >> 16);
}
__device__ __forceinline__ float bf2f(unsigned short h) {
  return __builtin_bit_cast(float, ((unsigned)h) << 16);
}

// ---------------- pre-pass: split+tile K and V (verified) ----------------
__global__ __launch_bounds__(256) void prepack(
    const float* __restrict__ K, const float* __restrict__ V,
    short* __restrict__ ws) {
  const int b  = blockIdx.x >> 7;
  const int kt = blockIdx.x & 127;
  const int t  = threadIdx.x;
  short* tile = ws + (size_t)(b * NKT + kt) * TILE_SHORTS;

  {  // K unit t: d8 = t>>5, key = t&31
    const int d8 = t >> 5, key = t & 31;
    const float* src = K + ((size_t)b * SS + kt * CH + key) * DH + d8 * 8;
    float4 a = ((const float4*)src)[0];
    float4 c = ((const float4*)src)[1];
    float v[8] = {a.x, a.y, a.z, a.w, c.x, c.y, c.z, c.w};
    bfrag hi, lo;
#pragma unroll
    for (int j = 0; j < 8; ++j) {
      unsigned short h = f2bf(v[j]);
      hi[j] = (short)h;
      lo[j] = (short)f2bf(v[j] - bf2f(h));
    }
    *(bfrag*)(tile + t * 8)        = hi;
    *(bfrag*)(tile + 2048 + t * 8) = lo;
  }
  {  // V unit t: k8 = t>>6, d = t&63
    const int k8 = t >> 6, d = t & 63;
    const float* src = V + ((size_t)b * SS + kt * CH + k8 * 8) * DH + d;
    bfrag hi, lo;
#pragma unroll
    for (int j = 0; j < 8; ++j) {
      float x = src[j * DH];
      unsigned short h = f2bf(x);
      hi[j] = (short)h;
      lo[j] = (short)f2bf(x - bf2f(h));
    }
    *(bfrag*)(tile + 4096 + t * 8) = hi;
    *(bfrag*)(tile + 6144 + t * 8) = lo;
  }
}

// ---------------- main fused attention ----------------
__global__ __launch_bounds__(256, 4) void attn_mfma(
    const float* __restrict__ Q, const short* __restrict__ wsT,
    const int* __restrict__ VL, float* __restrict__ Out,
    float* __restrict__ part_o, float* __restrict__ part_ml,
    int nsl, int sc) {
  // K-only double-buffer per pair: 2 pairs x 2 bufs x 8KB = 32 KB.
  __shared__ __align__(16) short sKV[2][2][KO_SHORTS];

  const int blk = blockIdx.x;
  const int slice = blk >> 9;            // 512 blocks per slice
  const int b   = (blk + slice) & 7;     // rotate batch->XCD per slice
  const int qt  = (blk >> 3) & 63;
  const int tid = threadIdx.x;
  const int w   = tid >> 6;
  const int l   = tid & 63;
  const int rg  = w & 1;    // row group: rows rg*32..+31
  const int p   = w >> 1;   // key-stripe pair within slice
  const int hi5 = l >> 5;
  const int l31 = l & 31;

  const int vlen = VL[b];
  const int nch  = (vlen + CH - 1) / CH;
  int nact = (nch + sc - 1) / sc;
  if (nact > nsl) nact = nsl;
  if (slice >= nact) return;             // uniform early exit (no barriers yet)
  const int c_lo = slice * sc;
  const int c_hi = min(c_lo + sc, nch);
  const int nchS = c_hi - c_lo;

  // ---- Q fragments (B-operand: col=l31=q-row), pre-scaled by 1/8 ----
  bfrag qh[4], ql[4];
  {
    const float* qsrc = Q + ((size_t)b * SS + qt * 64 + rg * 32 + l31) * DH;
#pragma unroll
    for (int dt = 0; dt < 4; ++dt) {
      const float* pp = qsrc + dt * 16 + hi5 * 8;
      float4 a = ((const float4*)pp)[0];
      float4 c = ((const float4*)pp)[1];
      float v[8] = {a.x, a.y, a.z, a.w, c.x, c.y, c.z, c.w};
#pragma unroll
      for (int j = 0; j < 8; ++j) {
        float x = v[j] * 0.125f;
        unsigned short h = f2bf(x);
        qh[dt][j] = (short)h;
        ql[dt][j] = (short)f2bf(x - bf2f(h));
      }
    }
  }

  f32x16 o0, o1;
#pragma unroll
  for (int r = 0; r < 16; ++r) { o0[r] = 0.f; o1[r] = 0.f; }
  float m = -1e30f, lsum = 0.f;

  const short* tbase = wsT + (size_t)b * NKT * TILE_SHORTS;

  // stage chunk ci's K part into sKV[p][buf]: 8 slots of 1KB, wave takes 4
  auto stage = [&](int ci, int buf) {
    const short* g = tbase + (size_t)ci * TILE_SHORTS;
    short* dst = &sKV[p][buf][0];
#pragma unroll
    for (int j = 0; j < 4; ++j) {
      const int s = j * 2 + rg;
      __builtin_amdgcn_global_load_lds(
          (const __attribute__((address_space(1))) void*)(g + s * 512 + l * 8),
          (__attribute__((address_space(3))) void*)(dst + s * 512 + l * 8),
          16, 0, 0);
    }
  };

  if (c_lo + p < c_hi) stage(c_lo + p, 0);

  const int T = (nchS + 1) >> 1;
  for (int t = 0; t < T; ++t) {
    __syncthreads();  // implicit vmcnt(0)+lgkmcnt(0): staged K ready
    const int ci  = c_lo + 2 * t + p;
    const int cur = t & 1;
    if (ci + 2 < c_hi) stage(ci + 2, cur ^ 1);  // prefetch under compute
    if (ci < c_hi) {
      const short* t0 = &sKV[p][cur][0];

      // ---- QK^T: acc[key][qrow], A=K B=Q; two 6-chains ----
      f32x16 accA, accB;
#pragma unroll
      for (int r = 0; r < 16; ++r) { accA[r] = 0.f; accB[r] = 0.f; }
#pragma unroll
      for (int dt = 0; dt < 4; ++dt) {
        bfrag kh = *(const bfrag*)(t0 + ((2 * dt + hi5) * 32 + l31) * 8);
        bfrag kl = *(const bfrag*)(t0 + 2048 + ((2 * dt + hi5) * 32 + l31) * 8);
        accA = __builtin_amdgcn_mfma_f32_32x32x16_bf16(kh, qh[dt], accA, 0, 0, 0);
        if (dt < 2)
          accA = __builtin_amdgcn_mfma_f32_32x32x16_bf16(kh, ql[dt], accA, 0, 0, 0);
        else
          accB = __builtin_amdgcn_mfma_f32_32x32x16_bf16(kh, ql[dt], accB, 0, 0, 0);
        accB = __builtin_amdgcn_mfma_f32_32x32x16_bf16(kl, qh[dt], accB, 0, 0, 0);
      }

      // accA/accB die here -> s[]; V loads issued AFTER so peak VGPR stays
      // under the 4-blocks/CU cap (no scratch spill).
      float s[16];
#pragma unroll
      for (int r = 0; r < 16; ++r) s[r] = accA[r] + accB[r];

      // ---- V fragments straight from packed ws (L2) into regs; the
      // mask+max+exp+cvt chain below (~150+ cyc) hides the L2 latency ----
      const short* gV = tbase + (size_t)ci * TILE_SHORTS;
      bfrag vh[2][2], vl[2][2];
#pragma unroll
      for (int ks = 0; ks < 2; ++ks) {
        const int vo = ((2 * ks + hi5) * 64 + l31) * 8;
        vh[ks][0] = *(const bfrag*)(gV + 4096 + vo);
        vl[ks][0] = *(const bfrag*)(gV + 6144 + vo);
        vh[ks][1] = *(const bfrag*)(gV + 4096 + vo + 256);
        vl[ks][1] = *(const bfrag*)(gV + 6144 + vo + 256);
      }

      // ---- mask tail keys ----
      const int c0 = ci * CH;
      if (c0 + CH > vlen) {
#pragma unroll
        for (int r = 0; r < 16; ++r) {
          int key = c0 + (r & 3) + 8 * (r >> 2) + 4 * hi5;
          if (key >= vlen) s[r] = -1e30f;
        }
      }

      // ---- online softmax (lane owns q-row l31) ----
      float cmax = s[0];
#pragma unroll
      for (int r = 1; r < 16; ++r) cmax = fmaxf(cmax, s[r]);
      cmax = fmaxf(cmax, __shfl_xor(cmax, 32));

      if (__any((int)(cmax > m + 8.0f))) {  // defer-max (T13)
        float mn = fmaxf(m, cmax);
        float sc2 = __expf(m - mn);
        m = mn;
        lsum *= sc2;
#pragma unroll
        for (int r = 0; r < 16; ++r) {
          float s2 = __shfl(sc2, (r & 3) + 8 * (r >> 2) + 4 * hi5);
          o0[r] *= s2;
          o1[r] *= s2;
        }
      }

      float ps = 0.f;
#pragma unroll
      for (int r = 0; r < 16; ++r) {
        s[r] = __expf(s[r] - m);
        ps += s[r];
      }
      ps += __shfl_xor(ps, 32);
      lsum += ps;

      // ---- P -> in-register A-fragments (cvt_pk + permlane32_swap) ----
      unsigned wh[8], wl2[8];
#pragma unroll
      for (int i = 0; i < 8; ++i) {
        float p0 = s[2 * i], p1 = s[2 * i + 1];
        unsigned hw;
        asm("v_cvt_pk_bf16_f32 %0, %1, %2" : "=v"(hw) : "v"(p0), "v"(p1));
        float h0 = __builtin_bit_cast(float, hw << 16);
        float h1 = __builtin_bit_cast(float, hw & 0xffff0000u);
        float r0 = p0 - h0, r1 = p1 - h1;
        unsigned lw;
        asm("v_cvt_pk_bf16_f32 %0, %1, %2" : "=v"(lw) : "v"(r0), "v"(r1));
        wh[i] = hw;
        wl2[i] = lw;
      }
      asm("v_permlane32_swap_b32 %0, %1" : "+v"(wh[0]), "+v"(wh[2]));
      asm("v_permlane32_swap_b32 %0, %1" : "+v"(wh[1]), "+v"(wh[3]));
      asm("v_permlane32_swap_b32 %0, %1" : "+v"(wh[4]), "+v"(wh[6]));
      asm("v_permlane32_swap_b32 %0, %1" : "+v"(wh[5]), "+v"(wh[7]));
      asm("v_permlane32_swap_b32 %0, %1" : "+v"(wl2[0]), "+v"(wl2[2]));
      asm("v_permlane32_swap_b32 %0, %1" : "+v"(wl2[1]), "+v"(wl2[3]));
      asm("v_permlane32_swap_b32 %0, %1" : "+v"(wl2[4]), "+v"(wl2[6]));
      asm("v_permlane32_swap_b32 %0, %1" : "+v"(wl2[5]), "+v"(wl2[7]));
      bfrag ph[2], pl[2];
      {
        uvec4 u0 = {wh[0], wh[1], wh[2], wh[3]};
        uvec4 u1 = {wh[4], wh[5], wh[6], wh[7]};
        uvec4 u2 = {wl2[0], wl2[1], wl2[2], wl2[3]};
        uvec4 u3 = {wl2[4], wl2[5], wl2[6], wl2[7]};
        ph[0] = __builtin_bit_cast(bfrag, u0);
        ph[1] = __builtin_bit_cast(bfrag, u1);
        pl[0] = __builtin_bit_cast(bfrag, u2);
        pl[1] = __builtin_bit_cast(bfrag, u3);
      }

      // ---- PV: o += P * V (A=P, B=V) ----
#pragma unroll
      for (int ks = 0; ks < 2; ++ks) {
        o0 = __builtin_amdgcn_mfma_f32_32x32x16_bf16(ph[ks], vh[ks][0], o0, 0, 0, 0);
        o0 = __builtin_amdgcn_mfma_f32_32x32x16_bf16(ph[ks], vl[ks][0], o0, 0, 0, 0);
        o0 = __builtin_amdgcn_mfma_f32_32x32x16_bf16(pl[ks], vh[ks][0], o0, 0, 0, 0);
        o1 = __builtin_amdgcn_mfma_f32_32x32x16_bf16(ph[ks], vh[ks][1], o1, 0, 0, 0);
        o1 = __builtin_amdgcn_mfma_f32_32x32x16_bf16(ph[ks], vl[ks][1], o1, 0, 0, 0);
        o1 = __builtin_amdgcn_mfma_f32_32x32x16_bf16(pl[ks], vh[ks][1], o1, 0, 0, 0);
      }
    }
  }

  // ---- epilogue: pair combine in (overlaid) LDS ----
  float* fl = (float*)&sKV[0][0][0];
  __syncthreads();
  if (hi5 == 0) {
    fl[p * 64 + rg * 32 + l31]       = m;
    fl[128 + p * 64 + rg * 32 + l31] = lsum;
  }
  __syncthreads();
  const float mo  = fl[(p ^ 1) * 64 + rg * 32 + l31];
  const float lo_ = fl[128 + (p ^ 1) * 64 + rg * 32 + l31];
  const float M   = fmaxf(m, mo);
  const float wgt = __expf(m - M);
  const float Lsum = lsum * wgt + lo_ * __expf(mo - M);
  const float linv = 1.0f / Lsum;
  float* C = fl + 256 + rg * 2048;
  if (p == 1) {
#pragma unroll
    for (int r = 0; r < 16; ++r) {
      int row = (r & 3) + 8 * (r >> 2) + 4 * hi5;
      float wr = __shfl(wgt, row);
      C[row * 64 + l31]      = wr * o0[r];
      C[row * 64 + 32 + l31] = wr * o1[r];
    }
  }
  __syncthreads();
  if (p == 0) {
    if (nact == 1) {  // sole slice: write final output directly
      float* ob = Out + ((size_t)b * SS + qt * 64 + rg * 32) * DH;
#pragma unroll
      for (int r = 0; r < 16; ++r) {
        int row = (r & 3) + 8 * (r >> 2) + 4 * hi5;
        float wr = __shfl(wgt, row);
        float li = __shfl(linv, row);
        ob[row * DH + l31]      = (wr * o0[r] + C[row * 64 + l31]) * li;
        ob[row * DH + 32 + l31] = (wr * o1[r] + C[row * 64 + 32 + l31]) * li;
      }
    } else {  // write slice partial (unnormalized, block-max-relative)
      const size_t base = (size_t)(b * 64 + qt) * nsl + slice;
      float* po = part_o + base * 4096 + rg * 32 * 64;
#pragma unroll
      for (int r = 0; r < 16; ++r) {
        int row = (r & 3) + 8 * (r >> 2) + 4 * hi5;
        float wr = __shfl(wgt, row);
        po[row * 64 + l31]      = wr * o0[r] + C[row * 64 + l31];
        po[row * 64 + 32 + l31] = wr * o1[r] + C[row * 64 + 32 + l31];
      }
      if (hi5 == 0) {
        part_ml[base * 128 + (rg * 32 + l31) * 2 + 0] = M;
        part_ml[base * 128 + (rg * 32 + l31) * 2 + 1] = Lsum;
      }
    }
  }
}

// ---------------- split-K combine ----------------
__global__ __launch_bounds__(256) void combine(
    const float* __restrict__ part_o, const float* __restrict__ part_ml,
    const int* __restrict__ VL, float* __restrict__ Out, int nsl, int sc) {
  const int blk = blockIdx.x;
  const int b = blk & 7, qt = blk >> 3;
  const int vlen = VL[b];
  const int nch = (vlen + CH - 1) / CH;
  int nact = (nch + sc - 1) / sc;
  if (nact > nsl) nact = nsl;
  if (nact < 2) return;  // attn wrote Out directly
  const int row = threadIdx.x >> 2;
  const int seg = (threadIdx.x & 3) * 16;
  const size_t base = (size_t)(b * 64 + qt) * nsl;

  float ms[4], ls[4];
  float M = -1e30f;
#pragma unroll
  for (int s = 0; s < 4; ++s) {
    if (s < nact) {
      ms[s] = part_ml[(base + s) * 128 + row * 2 + 0];
      ls[s] = part_ml[(base + s) * 128 + row * 2 + 1];
      M = fmaxf(M, ms[s]);
    } else { ms[s] = -1e30f; ls[s] = 0.f; }
  }
  float L = 0.f;
#pragma unroll
  for (int s = 0; s < 4; ++s) {
    ms[s] = __expf(ms[s] - M);
    L += ms[s] * ls[s];
  }
  const float linv = 1.0f / L;
  float4 acc[4];
#pragma unroll
  for (int j = 0; j < 4; ++j) acc[j] = make_float4(0.f, 0.f, 0.f, 0.f);
#pragma unroll
  for (int s = 0; s < 4; ++s) {
    if (s < nact) {
      const float4* po =
          (const float4*)(part_o + (base + s) * 4096 + row * 64 + seg);
#pragma unroll
      for (int j = 0; j < 4; ++j) {
        float4 v = po[j];
        acc[j].x += ms[s] * v.x;
        acc[j].y += ms[s] * v.y;
        acc[j].z += ms[s] * v.z;
        acc[j].w += ms[s] * v.w;
      }
    }
  }
  float4* op = (float4*)(Out + ((size_t)b * SS + qt * 64 + row) * DH + seg);
#pragma unroll
  for (int j = 0; j < 4; ++j) {
    acc[j].x *= linv; acc[j].y *= linv; acc[j].z *= linv; acc[j].w *= linv;
    op[j] = acc[j];
  }
}

// ---------------- emergency fallback (ws too small): naive flash ------------
__global__ __launch_bounds__(256) void attn_naive(
    const float* __restrict__ Q, const float* __restrict__ K,
    const float* __restrict__ V, const int* __restrict__ VL,
    float* __restrict__ Out) {
  const int row = blockIdx.x * 256 + threadIdx.x;
  const int b = row >> 12;
  const int vlen = VL[b];
  const float* q = Q + (size_t)row * DH;
  float qr[DH];
#pragma unroll
  for (int d = 0; d < DH; ++d) qr[d] = q[d] * 0.125f;
  float m = -1e30f, ls = 0.f, o[DH];
#pragma unroll
  for (int d = 0; d < DH; ++d) o[d] = 0.f;
  const float* Kb = K + (size_t)b * SS * DH;
  const float* Vb = V + (size_t)b * SS * DH;
  for (int k = 0; k < vlen; ++k) {
    float sc = 0.f;
    for (int d = 0; d < DH; ++d) sc += qr[d] * Kb[(size_t)k * DH + d];
    if (sc > m) {
      float scale = __expf(m - sc);
      m = sc;
      ls *= scale;
      for (int d = 0; d < DH; ++d) o[d] *= scale;
    }
    float pv = __expf(sc - m);
    ls += pv;
    for (int d = 0; d < DH; ++d) o[d] += pv * Vb[(size_t)k * DH + d];
  }
  for (int d = 0; d < DH; ++d) Out[(size_t)row * DH + d] = o[d] / ls;
}

extern "C" void kernel_launch(void* const* d_in, const int* in_sizes, int n_in,
                              void* d_out, int out_size, void* d_ws,
                              size_t ws_size, hipStream_t stream) {
  const float* Q  = (const float*)d_in[0];
  const float* K  = (const float*)d_in[1];
  const float* V  = (const float*)d_in[2];
  const int*   VL = (const int*)d_in[3];
  float* Out = (float*)d_out;

  const size_t pack_bytes = (size_t)BB * NKT * TILE_SHORTS * sizeof(short);  // 16 MB
  const size_t po_bytes   = (size_t)512 * 4 * 4096 * sizeof(float);          // 32 MB
  const size_t pml_bytes  = (size_t)512 * 4 * 128 * sizeof(float);           // 1 MB
  const size_t need_split = pack_bytes + po_bytes + pml_bytes;               // 51.4 MB

  if (ws_size >= need_split) {
    short* pack = (short*)d_ws;
    float* po   = (float*)((char*)d_ws + pack_bytes);
    float* pml  = (float*)((char*)d_ws + pack_bytes + po_bytes);
    prepack<<<dim3(BB * NKT), dim3(256), 0, stream>>>(K, V, pack);
    attn_mfma<<<dim3(4 * 512), dim3(256), 0, stream>>>(
        Q, pack, VL, Out, po, pml, 4, 32);
    combine<<<dim3(512), dim3(256), 0, stream>>>(po, pml, VL, Out, 4, 32);
  } else if (ws_size >= pack_bytes) {
    short* pack = (short*)d_ws;
    prepack<<<dim3(BB * NKT), dim3(256), 0, stream>>>(K, V, pack);
    attn_mfma<<<dim3(512), dim3(256), 0, stream>>>(
        Q, pack, VL, Out, (float*)d_ws, (float*)d_ws, 1, NKT);
  } else {
    attn_naive<<<dim3(BB * SS / 256), dim3(256), 0, stream>>>(Q, K, V, VL, Out);
  }
}

// Round 7
// 190.496 us; speedup vs baseline: 1.1450x; 1.1450x over previous
//
#include <hip/hip_runtime.h>
#include <stdint.h>

// DotProductAttention, B=8 S=4096 D=64 fp32, key-masked at valid_len[b].
// v4 = v2's proven inner loop (K AND V staged to LDS via global_load_lds,
// 64KB double-buffer, 121.6us measured) + 2-way split-K for CU load balance
// (the verified v3 gain) WITHOUT v3's regressions (no V-from-global, no
// batch->XCD rotation; b = blk&7 keeps each XCD's working set = one batch's
// 2MB pack slice, L2-resident).
//  - grid 1024 = (slice 0: chunks [0,64)) x 512 tiles + (slice 1: [64,128)).
//    Tiles with nch<=64 have one active slice -> write Out directly; heavy
//    tiles write per-slice partials (m, l, unnormalized o) merged by combine.

constexpr int BB = 8;
constexpr int SS = 4096;
constexpr int DH = 64;
constexpr int CH = 32;              // keys per chunk
constexpr int NKT = SS / CH;        // 128 chunks per batch
constexpr int TILE_SHORTS = 8192;   // 16 KB: Khi 4K | Klo 4K | Vhi 4K | Vlo 4K

typedef short  bfrag  __attribute__((ext_vector_type(8)));   // 8 bf16
typedef float  f32x16 __attribute__((ext_vector_type(16)));
typedef unsigned int uvec4 __attribute__((ext_vector_type(4)));

__device__ __forceinline__ unsigned short f2bf(float x) {
  unsigned u = __builtin_bit_cast(unsigned, x);
  u += 0x7fffu + ((u >> 16) & 1u);   // RNE
  return (unsigned short)(u >> 16);
}
__device__ __forceinline__ float bf2f(unsigned short h) {
  return __builtin_bit_cast(float, ((unsigned)h) << 16);
}

// ---------------- pre-pass: split+tile K and V (verified) ----------------
__global__ __launch_bounds__(256) void prepack(
    const float* __restrict__ K, const float* __restrict__ V,
    short* __restrict__ ws) {
  const int b  = blockIdx.x >> 7;
  const int kt = blockIdx.x & 127;
  const int t  = threadIdx.x;
  short* tile = ws + (size_t)(b * NKT + kt) * TILE_SHORTS;

  {  // K unit t: d8 = t>>5, key = t&31
    const int d8 = t >> 5, key = t & 31;
    const float* src = K + ((size_t)b * SS + kt * CH + key) * DH + d8 * 8;
    float4 a = ((const float4*)src)[0];
    float4 c = ((const float4*)src)[1];
    float v[8] = {a.x, a.y, a.z, a.w, c.x, c.y, c.z, c.w};
    bfrag hi, lo;
#pragma unroll
    for (int j = 0; j < 8; ++j) {
      unsigned short h = f2bf(v[j]);
      hi[j] = (short)h;
      lo[j] = (short)f2bf(v[j] - bf2f(h));
    }
    *(bfrag*)(tile + t * 8)        = hi;
    *(bfrag*)(tile + 2048 + t * 8) = lo;
  }
  {  // V unit t: k8 = t>>6, d = t&63
    const int k8 = t >> 6, d = t & 63;
    const float* src = V + ((size_t)b * SS + kt * CH + k8 * 8) * DH + d;
    bfrag hi, lo;
#pragma unroll
    for (int j = 0; j < 8; ++j) {
      float x = src[j * DH];
      unsigned short h = f2bf(x);
      hi[j] = (short)h;
      lo[j] = (short)f2bf(x - bf2f(h));
    }
    *(bfrag*)(tile + 4096 + t * 8) = hi;
    *(bfrag*)(tile + 6144 + t * 8) = lo;
  }
}

// ---------------- main fused attention ----------------
__global__ __launch_bounds__(256) void attn_mfma(
    const float* __restrict__ Q, const short* __restrict__ wsT,
    const int* __restrict__ VL, float* __restrict__ Out,
    float* __restrict__ part_o, float* __restrict__ part_ml,
    int nsl, int sc) {
  // [pair][dbuf][tile] = 64 KB; epilogue overlays the same memory.
  __shared__ __align__(16) short sKV[2][2][TILE_SHORTS];

  const int blk = blockIdx.x;
  const int slice = blk >> 9;       // 512 blocks per slice
  const int b   = blk & 7;          // NO rotation: XCD-local batch (L2-fit)
  const int qt  = (blk >> 3) & 63;
  const int tid = threadIdx.x;
  const int w   = tid >> 6;
  const int l   = tid & 63;
  const int rg  = w & 1;    // row group: rows rg*32..+31
  const int p   = w >> 1;   // key-stripe pair within slice
  const int hi5 = l >> 5;
  const int l31 = l & 31;

  const int vlen = VL[b];
  const int nch  = (vlen + CH - 1) / CH;
  int nact = (nch + sc - 1) / sc;
  if (nact > nsl) nact = nsl;
  if (slice >= nact) return;        // block-uniform exit before any barrier
  const int c_lo = slice * sc;
  const int c_hi = min(c_lo + sc, nch);
  const int nchS = c_hi - c_lo;

  // ---- Q fragments (B-operand: col=l31=q-row), pre-scaled by 1/8 ----
  bfrag qh[4], ql[4];
  {
    const float* qsrc = Q + ((size_t)b * SS + qt * 64 + rg * 32 + l31) * DH;
#pragma unroll
    for (int dt = 0; dt < 4; ++dt) {
      const float* pp = qsrc + dt * 16 + hi5 * 8;
      float4 a = ((const float4*)pp)[0];
      float4 c = ((const float4*)pp)[1];
      float v[8] = {a.x, a.y, a.z, a.w, c.x, c.y, c.z, c.w};
#pragma unroll
      for (int j = 0; j < 8; ++j) {
        float x = v[j] * 0.125f;
        unsigned short h = f2bf(x);
        qh[dt][j] = (short)h;
        ql[dt][j] = (short)f2bf(x - bf2f(h));
      }
    }
  }

  f32x16 o0, o1;
#pragma unroll
  for (int r = 0; r < 16; ++r) { o0[r] = 0.f; o1[r] = 0.f; }
  float m = -1e30f, lsum = 0.f;

  const short* tbase = wsT + (size_t)b * NKT * TILE_SHORTS;

  // stage full 16KB chunk ci into sKV[p][buf]: 16 slots of 1KB, wave takes 8
  auto stage = [&](int ci, int buf) {
    const short* g = tbase + (size_t)ci * TILE_SHORTS + l * 8;
    short* dst = &sKV[p][buf][0];
#pragma unroll
    for (int j = 0; j < 8; ++j) {
      const int s = j * 2 + rg;
      __builtin_amdgcn_global_load_lds(
          (const __attribute__((address_space(1))) void*)(g + s * 512),
          (__attribute__((address_space(3))) void*)(dst + s * 512),
          16, 0, 0);
    }
  };

  if (c_lo + p < c_hi) stage(c_lo + p, 0);

  const int T = (nchS + 1) >> 1;
  for (int t = 0; t < T; ++t) {
    __syncthreads();  // implicit vmcnt(0)+lgkmcnt(0): staged chunk ready
    const int ci  = c_lo + 2 * t + p;
    const int cur = t & 1;
    if (ci + 2 < c_hi) stage(ci + 2, cur ^ 1);  // prefetch under compute
    if (ci < c_hi) {
      const short* t0 = &sKV[p][cur][0];

      // ---- QK^T: acc[key][qrow], A=K B=Q; two 6-chains ----
      f32x16 accA, accB;
#pragma unroll
      for (int r = 0; r < 16; ++r) { accA[r] = 0.f; accB[r] = 0.f; }
#pragma unroll
      for (int dt = 0; dt < 4; ++dt) {
        bfrag kh = *(const bfrag*)(t0 + ((2 * dt + hi5) * 32 + l31) * 8);
        bfrag kl = *(const bfrag*)(t0 + 2048 + ((2 * dt + hi5) * 32 + l31) * 8);
        accA = __builtin_amdgcn_mfma_f32_32x32x16_bf16(kh, qh[dt], accA, 0, 0, 0);
        if (dt < 2)
          accA = __builtin_amdgcn_mfma_f32_32x32x16_bf16(kh, ql[dt], accA, 0, 0, 0);
        else
          accB = __builtin_amdgcn_mfma_f32_32x32x16_bf16(kh, ql[dt], accB, 0, 0, 0);
        accB = __builtin_amdgcn_mfma_f32_32x32x16_bf16(kl, qh[dt], accB, 0, 0, 0);
      }
      float s[16];
#pragma unroll
      for (int r = 0; r < 16; ++r) s[r] = accA[r] + accB[r];

      // ---- mask tail keys ----
      const int c0 = ci * CH;
      if (c0 + CH > vlen) {
#pragma unroll
        for (int r = 0; r < 16; ++r) {
          int key = c0 + (r & 3) + 8 * (r >> 2) + 4 * hi5;
          if (key >= vlen) s[r] = -1e30f;
        }
      }

      // ---- online softmax (lane owns q-row l31) ----
      float cmax = s[0];
#pragma unroll
      for (int r = 1; r < 16; ++r) cmax = fmaxf(cmax, s[r]);
      cmax = fmaxf(cmax, __shfl_xor(cmax, 32));

      if (__any((int)(cmax > m + 8.0f))) {  // defer-max (T13)
        float mn = fmaxf(m, cmax);
        float sc2 = __expf(m - mn);
        m = mn;
        lsum *= sc2;
#pragma unroll
        for (int r = 0; r < 16; ++r) {
          float s2 = __shfl(sc2, (r & 3) + 8 * (r >> 2) + 4 * hi5);
          o0[r] *= s2;
          o1[r] *= s2;
        }
      }

      float ps = 0.f;
#pragma unroll
      for (int r = 0; r < 16; ++r) {
        s[r] = __expf(s[r] - m);
        ps += s[r];
      }
      ps += __shfl_xor(ps, 32);
      lsum += ps;

      // ---- P -> in-register A-fragments (cvt_pk + permlane32_swap) ----
      unsigned wh[8], wl2[8];
#pragma unroll
      for (int i = 0; i < 8; ++i) {
        float p0 = s[2 * i], p1 = s[2 * i + 1];
        unsigned hw;
        asm("v_cvt_pk_bf16_f32 %0, %1, %2" : "=v"(hw) : "v"(p0), "v"(p1));
        float h0 = __builtin_bit_cast(float, hw << 16);
        float h1 = __builtin_bit_cast(float, hw & 0xffff0000u);
        float r0 = p0 - h0, r1 = p1 - h1;
        unsigned lw;
        asm("v_cvt_pk_bf16_f32 %0, %1, %2" : "=v"(lw) : "v"(r0), "v"(r1));
        wh[i] = hw;
        wl2[i] = lw;
      }
      asm("v_permlane32_swap_b32 %0, %1" : "+v"(wh[0]), "+v"(wh[2]));
      asm("v_permlane32_swap_b32 %0, %1" : "+v"(wh[1]), "+v"(wh[3]));
      asm("v_permlane32_swap_b32 %0, %1" : "+v"(wh[4]), "+v"(wh[6]));
      asm("v_permlane32_swap_b32 %0, %1" : "+v"(wh[5]), "+v"(wh[7]));
      asm("v_permlane32_swap_b32 %0, %1" : "+v"(wl2[0]), "+v"(wl2[2]));
      asm("v_permlane32_swap_b32 %0, %1" : "+v"(wl2[1]), "+v"(wl2[3]));
      asm("v_permlane32_swap_b32 %0, %1" : "+v"(wl2[4]), "+v"(wl2[6]));
      asm("v_permlane32_swap_b32 %0, %1" : "+v"(wl2[5]), "+v"(wl2[7]));
      bfrag ph[2], pl[2];
      {
        uvec4 u0 = {wh[0], wh[1], wh[2], wh[3]};
        uvec4 u1 = {wh[4], wh[5], wh[6], wh[7]};
        uvec4 u2 = {wl2[0], wl2[1], wl2[2], wl2[3]};
        uvec4 u3 = {wl2[4], wl2[5], wl2[6], wl2[7]};
        ph[0] = __builtin_bit_cast(bfrag, u0);
        ph[1] = __builtin_bit_cast(bfrag, u1);
        pl[0] = __builtin_bit_cast(bfrag, u2);
        pl[1] = __builtin_bit_cast(bfrag, u3);
      }

      // ---- PV: o += P * V (A=P, B=V); V from LDS (staged, conflict-free) ----
#pragma unroll
      for (int ks = 0; ks < 2; ++ks) {
        const int vo = ((2 * ks + hi5) * 64 + l31) * 8;
        bfrag vh0 = *(const bfrag*)(t0 + 4096 + vo);
        bfrag vl0 = *(const bfrag*)(t0 + 6144 + vo);
        bfrag vh1 = *(const bfrag*)(t0 + 4096 + vo + 256);
        bfrag vl1 = *(const bfrag*)(t0 + 6144 + vo + 256);
        o0 = __builtin_amdgcn_mfma_f32_32x32x16_bf16(ph[ks], vh0, o0, 0, 0, 0);
        o0 = __builtin_amdgcn_mfma_f32_32x32x16_bf16(ph[ks], vl0, o0, 0, 0, 0);
        o0 = __builtin_amdgcn_mfma_f32_32x32x16_bf16(pl[ks], vh0, o0, 0, 0, 0);
        o1 = __builtin_amdgcn_mfma_f32_32x32x16_bf16(ph[ks], vh1, o1, 0, 0, 0);
        o1 = __builtin_amdgcn_mfma_f32_32x32x16_bf16(ph[ks], vl1, o1, 0, 0, 0);
        o1 = __builtin_amdgcn_mfma_f32_32x32x16_bf16(pl[ks], vh1, o1, 0, 0, 0);
      }
    }
  }

  // ---- epilogue: pair combine in (overlaid) LDS ----
  float* fl = (float*)&sKV[0][0][0];
  __syncthreads();
  if (hi5 == 0) {
    fl[p * 64 + rg * 32 + l31]       = m;
    fl[128 + p * 64 + rg * 32 + l31] = lsum;
  }
  __syncthreads();
  const float mo  = fl[(p ^ 1) * 64 + rg * 32 + l31];
  const float lo_ = fl[128 + (p ^ 1) * 64 + rg * 32 + l31];
  const float M   = fmaxf(m, mo);
  const float wgt = __expf(m - M);
  const float Lsum = lsum * wgt + lo_ * __expf(mo - M);
  const float linv = 1.0f / Lsum;
  float* C = fl + 256 + rg * 2048;
  if (p == 1) {
#pragma unroll
    for (int r = 0; r < 16; ++r) {
      int row = (r & 3) + 8 * (r >> 2) + 4 * hi5;
      float wr = __shfl(wgt, row);
      C[row * 64 + l31]      = wr * o0[r];
      C[row * 64 + 32 + l31] = wr * o1[r];
    }
  }
  __syncthreads();
  if (p == 0) {
    if (nact == 1) {  // sole slice: write final output directly
      float* ob = Out + ((size_t)b * SS + qt * 64 + rg * 32) * DH;
#pragma unroll
      for (int r = 0; r < 16; ++r) {
        int row = (r & 3) + 8 * (r >> 2) + 4 * hi5;
        float wr = __shfl(wgt, row);
        float li = __shfl(linv, row);
        ob[row * DH + l31]      = (wr * o0[r] + C[row * 64 + l31]) * li;
        ob[row * DH + 32 + l31] = (wr * o1[r] + C[row * 64 + 32 + l31]) * li;
      }
    } else {  // write slice partial (unnormalized, block-max-relative)
      const size_t base = (size_t)(b * 64 + qt) * nsl + slice;
      float* po = part_o + base * 4096 + rg * 32 * 64;
#pragma unroll
      for (int r = 0; r < 16; ++r) {
        int row = (r & 3) + 8 * (r >> 2) + 4 * hi5;
        float wr = __shfl(wgt, row);
        po[row * 64 + l31]      = wr * o0[r] + C[row * 64 + l31];
        po[row * 64 + 32 + l31] = wr * o1[r] + C[row * 64 + 32 + l31];
      }
      if (hi5 == 0) {
        part_ml[base * 128 + (rg * 32 + l31) * 2 + 0] = M;
        part_ml[base * 128 + (rg * 32 + l31) * 2 + 1] = Lsum;
      }
    }
  }
}

// ---------------- split-K combine (2 slices) ----------------
__global__ __launch_bounds__(256) void combine(
    const float* __restrict__ part_o, const float* __restrict__ part_ml,
    const int* __restrict__ VL, float* __restrict__ Out, int nsl, int sc) {
  const int blk = blockIdx.x;
  const int b = blk & 7, qt = blk >> 3;
  const int vlen = VL[b];
  const int nch = (vlen + CH - 1) / CH;
  int nact = (nch + sc - 1) / sc;
  if (nact > nsl) nact = nsl;
  if (nact < 2) return;  // attn wrote Out directly
  const int row = threadIdx.x >> 2;
  const int seg = (threadIdx.x & 3) * 16;
  const size_t base = (size_t)(b * 64 + qt) * nsl;

  float m0 = part_ml[(base + 0) * 128 + row * 2 + 0];
  float l0 = part_ml[(base + 0) * 128 + row * 2 + 1];
  float m1 = part_ml[(base + 1) * 128 + row * 2 + 0];
  float l1 = part_ml[(base + 1) * 128 + row * 2 + 1];
  const float M = fmaxf(m0, m1);
  const float w0 = __expf(m0 - M), w1 = __expf(m1 - M);
  const float linv = 1.0f / (w0 * l0 + w1 * l1);

  const float4* p0 = (const float4*)(part_o + (base + 0) * 4096 + row * 64 + seg);
  const float4* p1 = (const float4*)(part_o + (base + 1) * 4096 + row * 64 + seg);
  float4* op = (float4*)(Out + ((size_t)b * SS + qt * 64 + row) * DH + seg);
#pragma unroll
  for (int j = 0; j < 4; ++j) {
    float4 a = p0[j], c = p1[j];
    float4 ov;
    ov.x = (w0 * a.x + w1 * c.x) * linv;
    ov.y = (w0 * a.y + w1 * c.y) * linv;
    ov.z = (w0 * a.z + w1 * c.z) * linv;
    ov.w = (w0 * a.w + w1 * c.w) * linv;
    op[j] = ov;
  }
}

// ---------------- emergency fallback (ws too small): naive flash ------------
__global__ __launch_bounds__(256) void attn_naive(
    const float* __restrict__ Q, const float* __restrict__ K,
    const float* __restrict__ V, const int* __restrict__ VL,
    float* __restrict__ Out) {
  const int row = blockIdx.x * 256 + threadIdx.x;
  const int b = row >> 12;
  const int vlen = VL[b];
  const float* q = Q + (size_t)row * DH;
  float qr[DH];
#pragma unroll
  for (int d = 0; d < DH; ++d) qr[d] = q[d] * 0.125f;
  float m = -1e30f, ls = 0.f, o[DH];
#pragma unroll
  for (int d = 0; d < DH; ++d) o[d] = 0.f;
  const float* Kb = K + (size_t)b * SS * DH;
  const float* Vb = V + (size_t)b * SS * DH;
  for (int k = 0; k < vlen; ++k) {
    float sc = 0.f;
    for (int d = 0; d < DH; ++d) sc += qr[d] * Kb[(size_t)k * DH + d];
    if (sc > m) {
      float scale = __expf(m - sc);
      m = sc;
      ls *= scale;
      for (int d = 0; d < DH; ++d) o[d] *= scale;
    }
    float pv = __expf(sc - m);
    ls += pv;
    for (int d = 0; d < DH; ++d) o[d] += pv * Vb[(size_t)k * DH + d];
  }
  for (int d = 0; d < DH; ++d) Out[(size_t)row * DH + d] = o[d] / ls;
}

extern "C" void kernel_launch(void* const* d_in, const int* in_sizes, int n_in,
                              void* d_out, int out_size, void* d_ws,
                              size_t ws_size, hipStream_t stream) {
  const float* Q  = (const float*)d_in[0];
  const float* K  = (const float*)d_in[1];
  const float* V  = (const float*)d_in[2];
  const int*   VL = (const int*)d_in[3];
  float* Out = (float*)d_out;

  const size_t pack_bytes = (size_t)BB * NKT * TILE_SHORTS * sizeof(short);  // 16 MB
  const size_t po_bytes   = (size_t)512 * 2 * 4096 * sizeof(float);          // 16 MB
  const size_t pml_bytes  = (size_t)512 * 2 * 128 * sizeof(float);           // 0.5 MB
  const size_t need_split = pack_bytes + po_bytes + pml_bytes;               // 32.5 MB

  if (ws_size >= need_split) {
    short* pack = (short*)d_ws;
    float* po   = (float*)((char*)d_ws + pack_bytes);
    float* pml  = (float*)((char*)d_ws + pack_bytes + po_bytes);
    prepack<<<dim3(BB * NKT), dim3(256), 0, stream>>>(K, V, pack);
    attn_mfma<<<dim3(2 * 512), dim3(256), 0, stream>>>(
        Q, pack, VL, Out, po, pml, 2, 64);
    combine<<<dim3(512), dim3(256), 0, stream>>>(po, pml, VL, Out, 2, 64);
  } else if (ws_size >= pack_bytes) {
    short* pack = (short*)d_ws;
    prepack<<<dim3(BB * NKT), dim3(256), 0, stream>>>(K, V, pack);
    attn_mfma<<<dim3(512), dim3(256), 0, stream>>>(
        Q, pack, VL, Out, (float*)d_ws, (float*)d_ws, 1, NKT);
  } else {
    attn_naive<<<dim3(BB * SS / 256), dim3(256), 0, stream>>>(Q, K, V, VL, Out);
  }
}

// Round 8
// 171.873 us; speedup vs baseline: 1.2691x; 1.1084x over previous
//
#include <hip/hip_runtime.h>
#include <stdint.h>

// DotProductAttention, B=8 S=4096 D=64 fp32, key-masked at valid_len[b].
// v5: error-compensated bf16 MFMA flash attention, occupancy-first.
//  - prepack (verified): K,V -> bf16 hi/lo 16KB tiles per 32-key chunk in ws.
//  - attn: block = 128 Q-rows x 4 waves (wave = 32 rows); ONE shared chunk
//    stream per block (no in-block key split): LDS = 2 dbuf x 16KB = 32KB ->
//    4 blocks/CU = 16 waves/CU = 4 waves/SIMD (2x v4) with K AND V in LDS.
//    Swapped QK^T (mfma(K,Q)); P in-register via v_cvt_pk_bf16_f32 +
//    v_permlane32_swap_b32; defer-max online softmax. Per-wave epilogue
//    (no cross-wave combine needed).
//  - split-K 4-way: grid 1024 = 256 tiles x 4 slices = exact resident
//    capacity; b=(blk>>3)&7 spreads every batch over all XCDs (balance)
//    while pack portions (512KB) stay L2/L3-resident. Partials merged by
//    combine kernel; single-active-slice tiles write Out directly.

constexpr int BB = 8;
constexpr int SS = 4096;
constexpr int DH = 64;
constexpr int CH = 32;              // keys per chunk
constexpr int NKT = SS / CH;        // 128 chunks per batch
constexpr int TILE_SHORTS = 8192;   // 16 KB: Khi 4K | Klo 4K | Vhi 4K | Vlo 4K
constexpr int NTILE = BB * (SS / 128);  // 256 output tiles of 128 rows
constexpr int NSL = 4;              // key slices
constexpr int SC = NKT / NSL;       // 32 chunks per slice

typedef short  bfrag  __attribute__((ext_vector_type(8)));   // 8 bf16
typedef float  f32x16 __attribute__((ext_vector_type(16)));
typedef unsigned int uvec4 __attribute__((ext_vector_type(4)));

__device__ __forceinline__ unsigned short f2bf(float x) {
  unsigned u = __builtin_bit_cast(unsigned, x);
  u += 0x7fffu + ((u >> 16) & 1u);   // RNE
  return (unsigned short)(u >> 16);
}
__device__ __forceinline__ float bf2f(unsigned short h) {
  return __builtin_bit_cast(float, ((unsigned)h) << 16);
}

// ---------------- pre-pass: split+tile K and V (verified) ----------------
__global__ __launch_bounds__(256) void prepack(
    const float* __restrict__ K, const float* __restrict__ V,
    short* __restrict__ ws) {
  const int b  = blockIdx.x >> 7;
  const int kt = blockIdx.x & 127;
  const int t  = threadIdx.x;
  short* tile = ws + (size_t)(b * NKT + kt) * TILE_SHORTS;

  {  // K unit t: d8 = t>>5, key = t&31
    const int d8 = t >> 5, key = t & 31;
    const float* src = K + ((size_t)b * SS + kt * CH + key) * DH + d8 * 8;
    float4 a = ((const float4*)src)[0];
    float4 c = ((const float4*)src)[1];
    float v[8] = {a.x, a.y, a.z, a.w, c.x, c.y, c.z, c.w};
    bfrag hi, lo;
#pragma unroll
    for (int j = 0; j < 8; ++j) {
      unsigned short h = f2bf(v[j]);
      hi[j] = (short)h;
      lo[j] = (short)f2bf(v[j] - bf2f(h));
    }
    *(bfrag*)(tile + t * 8)        = hi;
    *(bfrag*)(tile + 2048 + t * 8) = lo;
  }
  {  // V unit t: k8 = t>>6, d = t&63
    const int k8 = t >> 6, d = t & 63;
    const float* src = V + ((size_t)b * SS + kt * CH + k8 * 8) * DH + d;
    bfrag hi, lo;
#pragma unroll
    for (int j = 0; j < 8; ++j) {
      float x = src[j * DH];
      unsigned short h = f2bf(x);
      hi[j] = (short)h;
      lo[j] = (short)f2bf(x - bf2f(h));
    }
    *(bfrag*)(tile + 4096 + t * 8) = hi;
    *(bfrag*)(tile + 6144 + t * 8) = lo;
  }
}

// ---------------- main fused attention ----------------
__global__ __launch_bounds__(256, 4) void attn_mfma(
    const float* __restrict__ Q, const short* __restrict__ wsT,
    const int* __restrict__ VL, float* __restrict__ Out,
    float* __restrict__ part_o, float* __restrict__ part_ml, int nsl, int sc) {
  __shared__ __align__(16) short sKV[2][TILE_SHORTS];  // 32 KB double buffer

  const int blk = blockIdx.x;
  // b cycles every 8 blocks (spreads each batch over all XCDs; each XCD
  // hosts all batches); (qt, slice) from the remaining bits.
  const int b  = (blk >> 3) & 7;
  const int qs = ((blk >> 6) << 3) | (blk & 7);  // 0..127
  const int qt = qs >> 2;                        // 0..31 (128-row tile)
  const int slice = qs & 3;
  const int tid = threadIdx.x;
  const int w   = tid >> 6;   // wave = row group (w*32 rows)
  const int l   = tid & 63;
  const int hi5 = l >> 5;
  const int l31 = l & 31;

  const int vlen = VL[b];
  const int nch  = (vlen + CH - 1) / CH;
  int nact = (nch + sc - 1) / sc;
  if (nact > nsl) nact = nsl;
  if (slice >= nact) return;        // block-uniform exit before any barrier
  const int c_lo = slice * sc;
  const int c_hi = min(c_lo + sc, nch);
  const int nchS = c_hi - c_lo;

  // ---- Q fragments (B-operand: col=l31=q-row), pre-scaled by 1/8 ----
  bfrag qh[4], ql[4];
  {
    const float* qsrc = Q + ((size_t)b * SS + qt * 128 + w * 32 + l31) * DH;
#pragma unroll
    for (int dt = 0; dt < 4; ++dt) {
      const float* pp = qsrc + dt * 16 + hi5 * 8;
      float4 a = ((const float4*)pp)[0];
      float4 c = ((const float4*)pp)[1];
      float v[8] = {a.x, a.y, a.z, a.w, c.x, c.y, c.z, c.w};
#pragma unroll
      for (int j = 0; j < 8; ++j) {
        float x = v[j] * 0.125f;
        unsigned short h = f2bf(x);
        qh[dt][j] = (short)h;
        ql[dt][j] = (short)f2bf(x - bf2f(h));
      }
    }
  }

  f32x16 o0, o1;
#pragma unroll
  for (int r = 0; r < 16; ++r) { o0[r] = 0.f; o1[r] = 0.f; }
  float m = -1e30f, lsum = 0.f;

  const short* tbase = wsT + (size_t)b * NKT * TILE_SHORTS;

  // stage chunk ci (16KB) into sKV[buf]: 4 passes x (256 thr x 16B)
  auto stage = [&](int ci, int buf) {
    const short* g = tbase + (size_t)ci * TILE_SHORTS;
#pragma unroll
    for (int j = 0; j < 4; ++j) {
      __builtin_amdgcn_global_load_lds(
          (const __attribute__((address_space(1))) void*)(g + (j * 256 + tid) * 8),
          (__attribute__((address_space(3))) void*)(&sKV[buf][(j * 256 + tid) * 8]),
          16, 0, 0);
    }
  };

  stage(c_lo, 0);

  for (int t = 0; t < nchS; ++t) {
    __syncthreads();  // implicit vmcnt(0)+lgkmcnt(0): staged chunk ready
    const int ci  = c_lo + t;
    const int cur = t & 1;
    if (t + 1 < nchS) stage(ci + 1, cur ^ 1);  // prefetch under compute
    const short* t0 = &sKV[cur][0];

    // ---- QK^T: acc[key][qrow], A=K B=Q; two 6-chains ----
    f32x16 accA, accB;
#pragma unroll
    for (int r = 0; r < 16; ++r) { accA[r] = 0.f; accB[r] = 0.f; }
#pragma unroll
    for (int dt = 0; dt < 4; ++dt) {
      bfrag kh = *(const bfrag*)(t0 + ((2 * dt + hi5) * 32 + l31) * 8);
      bfrag kl = *(const bfrag*)(t0 + 2048 + ((2 * dt + hi5) * 32 + l31) * 8);
      accA = __builtin_amdgcn_mfma_f32_32x32x16_bf16(kh, qh[dt], accA, 0, 0, 0);
      if (dt < 2)
        accA = __builtin_amdgcn_mfma_f32_32x32x16_bf16(kh, ql[dt], accA, 0, 0, 0);
      else
        accB = __builtin_amdgcn_mfma_f32_32x32x16_bf16(kh, ql[dt], accB, 0, 0, 0);
      accB = __builtin_amdgcn_mfma_f32_32x32x16_bf16(kl, qh[dt], accB, 0, 0, 0);
    }
    float s[16];
#pragma unroll
    for (int r = 0; r < 16; ++r) s[r] = accA[r] + accB[r];

    // ---- mask tail keys ----
    const int c0 = ci * CH;
    if (c0 + CH > vlen) {
#pragma unroll
      for (int r = 0; r < 16; ++r) {
        int key = c0 + (r & 3) + 8 * (r >> 2) + 4 * hi5;
        if (key >= vlen) s[r] = -1e30f;
      }
    }

    // ---- online softmax (lane owns q-row l31) ----
    float cmax = s[0];
#pragma unroll
    for (int r = 1; r < 16; ++r) cmax = fmaxf(cmax, s[r]);
    cmax = fmaxf(cmax, __shfl_xor(cmax, 32));

    if (__any((int)(cmax > m + 8.0f))) {  // defer-max (T13)
      float mn = fmaxf(m, cmax);
      float sc2 = __expf(m - mn);
      m = mn;
      lsum *= sc2;
#pragma unroll
      for (int r = 0; r < 16; ++r) {
        float s2 = __shfl(sc2, (r & 3) + 8 * (r >> 2) + 4 * hi5);
        o0[r] *= s2;
        o1[r] *= s2;
      }
    }

    float ps = 0.f;
#pragma unroll
    for (int r = 0; r < 16; ++r) {
      s[r] = __expf(s[r] - m);
      ps += s[r];
    }
    ps += __shfl_xor(ps, 32);
    lsum += ps;

    // ---- P -> in-register A-fragments (cvt_pk + permlane32_swap) ----
    unsigned wh[8], wl2[8];
#pragma unroll
    for (int i = 0; i < 8; ++i) {
      float p0 = s[2 * i], p1 = s[2 * i + 1];
      unsigned hw;
      asm("v_cvt_pk_bf16_f32 %0, %1, %2" : "=v"(hw) : "v"(p0), "v"(p1));
      float h0 = __builtin_bit_cast(float, hw << 16);
      float h1 = __builtin_bit_cast(float, hw & 0xffff0000u);
      float r0 = p0 - h0, r1 = p1 - h1;
      unsigned lw;
      asm("v_cvt_pk_bf16_f32 %0, %1, %2" : "=v"(lw) : "v"(r0), "v"(r1));
      wh[i] = hw;
      wl2[i] = lw;
    }
    asm("v_permlane32_swap_b32 %0, %1" : "+v"(wh[0]), "+v"(wh[2]));
    asm("v_permlane32_swap_b32 %0, %1" : "+v"(wh[1]), "+v"(wh[3]));
    asm("v_permlane32_swap_b32 %0, %1" : "+v"(wh[4]), "+v"(wh[6]));
    asm("v_permlane32_swap_b32 %0, %1" : "+v"(wh[5]), "+v"(wh[7]));
    asm("v_permlane32_swap_b32 %0, %1" : "+v"(wl2[0]), "+v"(wl2[2]));
    asm("v_permlane32_swap_b32 %0, %1" : "+v"(wl2[1]), "+v"(wl2[3]));
    asm("v_permlane32_swap_b32 %0, %1" : "+v"(wl2[4]), "+v"(wl2[6]));
    asm("v_permlane32_swap_b32 %0, %1" : "+v"(wl2[5]), "+v"(wl2[7]));
    bfrag ph[2], pl[2];
    {
      uvec4 u0 = {wh[0], wh[1], wh[2], wh[3]};
      uvec4 u1 = {wh[4], wh[5], wh[6], wh[7]};
      uvec4 u2 = {wl2[0], wl2[1], wl2[2], wl2[3]};
      uvec4 u3 = {wl2[4], wl2[5], wl2[6], wl2[7]};
      ph[0] = __builtin_bit_cast(bfrag, u0);
      ph[1] = __builtin_bit_cast(bfrag, u1);
      pl[0] = __builtin_bit_cast(bfrag, u2);
      pl[1] = __builtin_bit_cast(bfrag, u3);
    }

    // ---- PV: o += P * V (A=P, B=V); V from LDS (staged, conflict-free) ----
#pragma unroll
    for (int ks = 0; ks < 2; ++ks) {
      const int vo = ((2 * ks + hi5) * 64 + l31) * 8;
      bfrag vh0 = *(const bfrag*)(t0 + 4096 + vo);
      bfrag vl0 = *(const bfrag*)(t0 + 6144 + vo);
      bfrag vh1 = *(const bfrag*)(t0 + 4096 + vo + 256);
      bfrag vl1 = *(const bfrag*)(t0 + 6144 + vo + 256);
      o0 = __builtin_amdgcn_mfma_f32_32x32x16_bf16(ph[ks], vh0, o0, 0, 0, 0);
      o0 = __builtin_amdgcn_mfma_f32_32x32x16_bf16(ph[ks], vl0, o0, 0, 0, 0);
      o0 = __builtin_amdgcn_mfma_f32_32x32x16_bf16(pl[ks], vh0, o0, 0, 0, 0);
      o1 = __builtin_amdgcn_mfma_f32_32x32x16_bf16(ph[ks], vh1, o1, 0, 0, 0);
      o1 = __builtin_amdgcn_mfma_f32_32x32x16_bf16(ph[ks], vl1, o1, 0, 0, 0);
      o1 = __builtin_amdgcn_mfma_f32_32x32x16_bf16(pl[ks], vh1, o1, 0, 0, 0);
    }
  }

  // ---- per-wave epilogue (wave owns its 32 rows exclusively) ----
  const float linv = 1.0f / lsum;
  if (nact == 1) {  // sole slice: final output
    float* ob = Out + ((size_t)b * SS + qt * 128 + w * 32) * DH;
#pragma unroll
    for (int r = 0; r < 16; ++r) {
      int row = (r & 3) + 8 * (r >> 2) + 4 * hi5;
      float li = __shfl(linv, row);
      ob[row * DH + l31]      = o0[r] * li;
      ob[row * DH + 32 + l31] = o1[r] * li;
    }
  } else {  // slice partial: unnormalized o + (m, lsum) per row
    const size_t base = (size_t)((b * 32 + qt) * nsl + slice);
    float* po = part_o + base * 8192 + w * 32 * 64;
#pragma unroll
    for (int r = 0; r < 16; ++r) {
      int row = (r & 3) + 8 * (r >> 2) + 4 * hi5;
      po[row * 64 + l31]      = o0[r];
      po[row * 64 + 32 + l31] = o1[r];
    }
    if (hi5 == 0) {
      part_ml[base * 256 + (w * 32 + l31) * 2 + 0] = m;
      part_ml[base * 256 + (w * 32 + l31) * 2 + 1] = lsum;
    }
  }
}

// ---------------- split-K combine (up to 4 slices, 128-row tiles) ----------
__global__ __launch_bounds__(256) void combine(
    const float* __restrict__ part_o, const float* __restrict__ part_ml,
    const int* __restrict__ VL, float* __restrict__ Out, int nsl, int sc) {
  const int blk = blockIdx.x;           // 256 tiles
  const int b = blk & 7, qt = blk >> 3; // qt 0..31
  const int vlen = VL[b];
  const int nch = (vlen + CH - 1) / CH;
  int nact = (nch + sc - 1) / sc;
  if (nact > nsl) nact = nsl;
  if (nact < 2) return;  // attn wrote Out directly
  const int row = threadIdx.x >> 1;          // 0..127
  const int seg = (threadIdx.x & 1) * 32;    // half-row of 32 floats
  const size_t base = (size_t)(b * 32 + qt) * nsl;

  float ms[4], ls[4];
  float M = -1e30f;
#pragma unroll
  for (int s = 0; s < 4; ++s) {
    if (s < nact) {
      ms[s] = part_ml[(base + s) * 256 + row * 2 + 0];
      ls[s] = part_ml[(base + s) * 256 + row * 2 + 1];
      M = fmaxf(M, ms[s]);
    } else { ms[s] = -1e30f; ls[s] = 0.f; }
  }
  float L = 0.f;
#pragma unroll
  for (int s = 0; s < 4; ++s) {
    ms[s] = __expf(ms[s] - M);   // weight
    L += ms[s] * ls[s];
  }
  const float linv = 1.0f / L;

  float4 acc[8];
#pragma unroll
  for (int j = 0; j < 8; ++j) acc[j] = make_float4(0.f, 0.f, 0.f, 0.f);
#pragma unroll
  for (int s = 0; s < 4; ++s) {
    if (s < nact) {
      const float4* po =
          (const float4*)(part_o + (base + s) * 8192 + row * 64 + seg);
#pragma unroll
      for (int j = 0; j < 8; ++j) {
        float4 v = po[j];
        acc[j].x += ms[s] * v.x;
        acc[j].y += ms[s] * v.y;
        acc[j].z += ms[s] * v.z;
        acc[j].w += ms[s] * v.w;
      }
    }
  }
  float4* op = (float4*)(Out + ((size_t)b * SS + qt * 128 + row) * DH + seg);
#pragma unroll
  for (int j = 0; j < 8; ++j) {
    acc[j].x *= linv; acc[j].y *= linv; acc[j].z *= linv; acc[j].w *= linv;
    op[j] = acc[j];
  }
}

// ---------------- emergency fallback (ws too small): naive flash ------------
__global__ __launch_bounds__(256) void attn_naive(
    const float* __restrict__ Q, const float* __restrict__ K,
    const float* __restrict__ V, const int* __restrict__ VL,
    float* __restrict__ Out) {
  const int row = blockIdx.x * 256 + threadIdx.x;
  const int b = row >> 12;
  const int vlen = VL[b];
  const float* q = Q + (size_t)row * DH;
  float qr[DH];
#pragma unroll
  for (int d = 0; d < DH; ++d) qr[d] = q[d] * 0.125f;
  float m = -1e30f, ls = 0.f, o[DH];
#pragma unroll
  for (int d = 0; d < DH; ++d) o[d] = 0.f;
  const float* Kb = K + (size_t)b * SS * DH;
  const float* Vb = V + (size_t)b * SS * DH;
  for (int k = 0; k < vlen; ++k) {
    float sc = 0.f;
    for (int d = 0; d < DH; ++d) sc += qr[d] * Kb[(size_t)k * DH + d];
    if (sc > m) {
      float scale = __expf(m - sc);
      m = sc;
      ls *= scale;
      for (int d = 0; d < DH; ++d) o[d] *= scale;
    }
    float pv = __expf(sc - m);
    ls += pv;
    for (int d = 0; d < DH; ++d) o[d] += pv * Vb[(size_t)k * DH + d];
  }
  for (int d = 0; d < DH; ++d) Out[(size_t)row * DH + d] = o[d] / ls;
}

extern "C" void kernel_launch(void* const* d_in, const int* in_sizes, int n_in,
                              void* d_out, int out_size, void* d_ws,
                              size_t ws_size, hipStream_t stream) {
  const float* Q  = (const float*)d_in[0];
  const float* K  = (const float*)d_in[1];
  const float* V  = (const float*)d_in[2];
  const int*   VL = (const int*)d_in[3];
  float* Out = (float*)d_out;

  const size_t pack_bytes = (size_t)BB * NKT * TILE_SHORTS * sizeof(short);     // 16 MB
  const size_t po_bytes   = (size_t)NTILE * NSL * 8192 * sizeof(float);         // 32 MB
  const size_t pml_bytes  = (size_t)NTILE * NSL * 256 * sizeof(float);          // 1 MB
  const size_t need_split = pack_bytes + po_bytes + pml_bytes;                  // 49 MB

  if (ws_size >= need_split) {
    short* pack = (short*)d_ws;
    float* po   = (float*)((char*)d_ws + pack_bytes);
    float* pml  = (float*)((char*)d_ws + pack_bytes + po_bytes);
    prepack<<<dim3(BB * NKT), dim3(256), 0, stream>>>(K, V, pack);
    attn_mfma<<<dim3(NTILE * NSL), dim3(256), 0, stream>>>(
        Q, pack, VL, Out, po, pml, NSL, SC);
    combine<<<dim3(NTILE), dim3(256), 0, stream>>>(po, pml, VL, Out, NSL, SC);
  } else if (ws_size >= pack_bytes) {
    short* pack = (short*)d_ws;
    prepack<<<dim3(BB * NKT), dim3(256), 0, stream>>>(K, V, pack);
    attn_mfma<<<dim3(NTILE), dim3(256), 0, stream>>>(
        Q, pack, VL, Out, (float*)d_ws, (float*)d_ws, 1, NKT);
  } else {
    attn_naive<<<dim3(BB * SS / 256), dim3(256), 0, stream>>>(Q, K, V, VL, Out);
  }
}